// Round 1
// baseline (701.080 us; speedup 1.0000x reference)
//
#include <hip/hip_runtime.h>
#include <cstddef>

#define BATCH 64
#define CCH   512
#define RCH   32
#define HW    1024
#define SSTRIDE 1028   // 1028*4 = 4112 bytes: 16B-aligned rows, bank-shifted by 4

// ---------------- K0: Wcomb = W_restore @ W_mask  (512x32) ----------------
__global__ __launch_bounds__(256) void k_wcomb(const float* __restrict__ Wrest,
                                               const float* __restrict__ Wmask,
                                               float* __restrict__ Wcomb) {
  int tid = blockIdx.x * 256 + threadIdx.x;
  if (tid >= CCH * RCH) return;
  int co = tid >> 5, r = tid & 31;
  float a = 0.f;
#pragma unroll
  for (int rp = 0; rp < RCH; ++rp)
    a += Wrest[co * RCH + rp] * Wmask[rp * RCH + r];
  Wcomb[tid] = a;
}

// ---------------- K1: xr = Wred@x ; phi/theta/g = Wphi/Wth/Wg @ xr --------
__global__ __launch_bounds__(256) void k_reduce(const float* __restrict__ x,
    const float* __restrict__ Wred, const float* __restrict__ Wphi,
    const float* __restrict__ Wth,  const float* __restrict__ Wg,
    const float* __restrict__ posdec,
    float* __restrict__ phi, float* __restrict__ theta, float* __restrict__ g) {
  int gid = blockIdx.x * 256 + threadIdx.x;   // 64*1024 columns total
  int b = gid >> 10, n = gid & 1023;
  const float* xb = x + ((size_t)b * CCH) * HW + n;

  float acc[RCH];
#pragma unroll
  for (int r = 0; r < RCH; ++r) acc[r] = 0.f;

  for (int c = 0; c < CCH; c += 4) {
    float x0 = xb[(size_t)(c + 0) * HW];
    float x1 = xb[(size_t)(c + 1) * HW];
    float x2 = xb[(size_t)(c + 2) * HW];
    float x3 = xb[(size_t)(c + 3) * HW];
#pragma unroll
    for (int r = 0; r < RCH; ++r) {
      const float4 w = *(const float4*)(Wred + r * CCH + c);  // uniform -> s_load
      acc[r] += w.x * x0 + w.y * x1 + w.z * x2 + w.w * x3;
    }
  }

  size_t base = ((size_t)b * RCH) * HW + n;
#pragma unroll
  for (int r = 0; r < RCH; ++r) {
    float p = 0.f, t = 0.f, gg = 0.f;
#pragma unroll
    for (int q = 0; q < RCH; q += 4) {
      const float4 wp = *(const float4*)(Wphi + r * RCH + q);
      const float4 wt = *(const float4*)(Wth  + r * RCH + q);
      const float4 wg = *(const float4*)(Wg   + r * RCH + q);
      p  += wp.x * acc[q] + wp.y * acc[q + 1] + wp.z * acc[q + 2] + wp.w * acc[q + 3];
      t  += wt.x * acc[q] + wt.y * acc[q + 1] + wt.z * acc[q + 2] + wt.w * acc[q + 3];
      gg += wg.x * acc[q] + wg.y * acc[q + 1] + wg.z * acc[q + 2] + wg.w * acc[q + 3];
    }
    phi[base + (size_t)r * HW]   = p;
    theta[base + (size_t)r * HW] = t;
    g[base + (size_t)r * HW]     = gg + posdec[r * HW + n];
  }
}

// ---------------- K2: attention for 32 query rows per block ---------------
// S[n][m] = sum_r theta[r][n0+n]*phi[r][m] + pos[n0+n][m]; softmax over m;
// y[n][r] = sum_m P[n][m]*g[r][m]; y2[b][r][n0+n] = y[n][r]/rowsum
__global__ __launch_bounds__(512) void k_attn(const float* __restrict__ phi,
    const float* __restrict__ theta, const float* __restrict__ g,
    const float* __restrict__ pos, float* __restrict__ y2) {
  __shared__ float S[RCH][SSTRIDE];          // 131584 B
  __shared__ float part[4][RCH][RCH + 1];    // 16896 B
  __shared__ float rsum[RCH];

  const int t    = threadIdx.x;
  const int b    = blockIdx.y;
  const int n0   = blockIdx.x * RCH;
  const int wv   = t >> 6;                   // wave 0..7
  const int lane = t & 63;

  // ---- QK^T + pos -> S ----
  {
    float acc[4][16];
#pragma unroll
    for (int i = 0; i < 4; ++i)
#pragma unroll
      for (int j = 0; j < 16; ++j) acc[i][j] = 0.f;

    const float* phib = phi + ((size_t)b * RCH) * HW;
    const float* thb  = theta + ((size_t)b * RCH) * HW + n0 + wv * 4;

    for (int r = 0; r < RCH; ++r) {
      float4 pv[4];
#pragma unroll
      for (int k = 0; k < 4; ++k)
        pv[k] = *(const float4*)(phib + (size_t)r * HW + (k << 8) + (lane << 2));
      float tv[4];
#pragma unroll
      for (int i = 0; i < 4; ++i) tv[i] = thb[(size_t)r * HW + i];  // wave-uniform
#pragma unroll
      for (int i = 0; i < 4; ++i)
#pragma unroll
        for (int k = 0; k < 4; ++k) {
          acc[i][4 * k + 0] += tv[i] * pv[k].x;
          acc[i][4 * k + 1] += tv[i] * pv[k].y;
          acc[i][4 * k + 2] += tv[i] * pv[k].z;
          acc[i][4 * k + 3] += tv[i] * pv[k].w;
        }
    }
#pragma unroll
    for (int i = 0; i < 4; ++i) {
      int n = wv * 4 + i;
#pragma unroll
      for (int k = 0; k < 4; ++k) {
        float4 pe = *(const float4*)(pos + (size_t)(n0 + n) * HW + (k << 8) + (lane << 2));
        float4 sv;
        sv.x = acc[i][4 * k + 0] + pe.x;
        sv.y = acc[i][4 * k + 1] + pe.y;
        sv.z = acc[i][4 * k + 2] + pe.z;
        sv.w = acc[i][4 * k + 3] + pe.w;
        *(float4*)&S[n][(k << 8) + (lane << 2)] = sv;
      }
    }
  }
  __syncthreads();

  // ---- softmax over each row (16 threads per row) ----
  {
    int row = t >> 4, col = t & 15;
    float mx = -1e30f;
    for (int k = 0; k < 64; ++k) mx = fmaxf(mx, S[row][col + (k << 4)]);
#pragma unroll
    for (int off = 1; off < 16; off <<= 1) mx = fmaxf(mx, __shfl_xor(mx, off, 64));
    float sum = 0.f;
    for (int k = 0; k < 64; ++k) {
      int m = col + (k << 4);
      float p = __expf(S[row][m] - mx);
      S[row][m] = p;
      sum += p;
    }
#pragma unroll
    for (int off = 1; off < 16; off <<= 1) sum += __shfl_xor(sum, off, 64);
    if (col == 0) rsum[row] = 1.f / sum;
  }
  __syncthreads();

  // ---- PV: wave w handles m in [w*128, w*128+128), micro-tile 4n x 4r ----
  const int ng = lane >> 3, rg = lane & 7;
  float y[4][4];
#pragma unroll
  for (int i = 0; i < 4; ++i)
#pragma unroll
    for (int j = 0; j < 4; ++j) y[i][j] = 0.f;

  const float* gb = g + ((size_t)b * RCH) * HW;
  const int mb = wv << 7;
  for (int mi = 0; mi < 32; ++mi) {
    int m4 = mb + (mi << 2);
    float4 pv[4];
#pragma unroll
    for (int i = 0; i < 4; ++i) pv[i] = *(const float4*)&S[ng * 4 + i][m4];
#pragma unroll
    for (int j = 0; j < 4; ++j) {
      float4 gv = *(const float4*)(gb + (size_t)(rg * 4 + j) * HW + m4);
#pragma unroll
      for (int i = 0; i < 4; ++i)
        y[i][j] += pv[i].x * gv.x + pv[i].y * gv.y + pv[i].z * gv.z + pv[i].w * gv.w;
    }
  }

  // ---- tree-reduce partial y across 8 waves: 8 -> 4 -> 2 -> 1 ----
#pragma unroll
  for (int half = 4; half >= 1; half >>= 1) {
    if (wv >= half && wv < 2 * half) {
#pragma unroll
      for (int i = 0; i < 4; ++i)
#pragma unroll
        for (int j = 0; j < 4; ++j)
          part[wv - half][ng * 4 + i][rg * 4 + j] = y[i][j];
    }
    __syncthreads();
    if (wv < half) {
#pragma unroll
      for (int i = 0; i < 4; ++i)
#pragma unroll
        for (int j = 0; j < 4; ++j)
          y[i][j] += part[wv][ng * 4 + i][rg * 4 + j];
    }
    __syncthreads();
  }
  if (wv == 0) {
#pragma unroll
    for (int i = 0; i < 4; ++i)
#pragma unroll
      for (int j = 0; j < 4; ++j)
        part[0][ng * 4 + i][rg * 4 + j] = y[i][j];
  }
  __syncthreads();

  // ---- scale by 1/rowsum and store coalesced ----
  float* y2b = y2 + ((size_t)b * RCH) * HW + n0;
  for (int o = t; o < RCH * RCH; o += 512) {
    int r = o >> 5, n = o & 31;
    y2b[(size_t)r * HW + n] = part[0][n][r] * rsum[n];
  }
}

// ---------------- K3: out = x + Wcomb @ y2 --------------------------------
__global__ __launch_bounds__(256) void k_restore(const float* __restrict__ x,
    const float* __restrict__ Wcomb, const float* __restrict__ y2,
    float* __restrict__ out) {
  int gid = blockIdx.x * 256 + threadIdx.x;
  int b = gid >> 10, n = gid & 1023;

  float yv[RCH];
  const float* y2b = y2 + ((size_t)b * RCH) * HW + n;
#pragma unroll
  for (int r = 0; r < RCH; ++r) yv[r] = y2b[(size_t)r * HW];

  const float* xb = x + ((size_t)b * CCH) * HW + n;
  float* ob = out + ((size_t)b * CCH) * HW + n;
  for (int co = 0; co < CCH; ++co) {
    float a = xb[(size_t)co * HW];
#pragma unroll
    for (int q = 0; q < RCH; q += 4) {
      const float4 w = *(const float4*)(Wcomb + co * RCH + q);  // uniform -> s_load
      a += w.x * yv[q] + w.y * yv[q + 1] + w.z * yv[q + 2] + w.w * yv[q + 3];
    }
    ob[(size_t)co * HW] = a;
  }
}

extern "C" void kernel_launch(void* const* d_in, const int* in_sizes, int n_in,
                              void* d_out, int out_size, void* d_ws, size_t ws_size,
                              hipStream_t stream) {
  const float* x      = (const float*)d_in[0];
  const float* Wred   = (const float*)d_in[1];
  const float* Wrest  = (const float*)d_in[2];
  const float* Wphi   = (const float*)d_in[3];
  const float* Wth    = (const float*)d_in[4];
  const float* Wg     = (const float*)d_in[5];
  const float* Wmask  = (const float*)d_in[6];
  const float* pos    = (const float*)d_in[7];
  const float* posdec = (const float*)d_in[8];
  float* out = (float*)d_out;
  float* ws  = (float*)d_ws;

  const size_t NPB = (size_t)BATCH * RCH * HW;  // 2M floats per intermediate
  float* phi   = ws;
  float* theta = ws + NPB;
  float* g     = ws + 2 * NPB;
  float* y2    = ws + 3 * NPB;
  float* Wcomb = ws + 4 * NPB;  // 16384 floats

  k_wcomb  <<<dim3(64),       dim3(256), 0, stream>>>(Wrest, Wmask, Wcomb);
  k_reduce <<<dim3(256),      dim3(256), 0, stream>>>(x, Wred, Wphi, Wth, Wg, posdec,
                                                      phi, theta, g);
  k_attn   <<<dim3(32, 64),   dim3(512), 0, stream>>>(phi, theta, g, pos, y2);
  k_restore<<<dim3(256),      dim3(256), 0, stream>>>(x, Wcomb, y2, out);
}

// Round 2
// 280.963 us; speedup vs baseline: 2.4953x; 2.4953x over previous
//
#include <hip/hip_runtime.h>
#include <cstddef>

#define BATCH 64
#define CCH   512
#define RCH   32
#define HW    1024
#define QBLK  16
#define PSTR  1032   // P_lds row stride in bf16 elems (pads banks, keeps 16B align)

typedef __attribute__((ext_vector_type(8))) short short8;
typedef __attribute__((ext_vector_type(4))) float f32x4;

__device__ inline ushort f2b(float f) {   // f32 -> bf16 bits, RNE
  union { float f; uint u; } x{f};
  uint r = x.u + 0x7FFFu + ((x.u >> 16) & 1u);
  return (ushort)(r >> 16);
}

// ---------------- K0: Wcomb = W_restore @ W_mask  (512x32) ----------------
__global__ __launch_bounds__(256) void k_wcomb(const float* __restrict__ Wrest,
                                               const float* __restrict__ Wmask,
                                               float* __restrict__ Wcomb) {
  int tid = blockIdx.x * 256 + threadIdx.x;
  if (tid >= CCH * RCH) return;
  int co = tid >> 5, r = tid & 31;
  float a = 0.f;
#pragma unroll
  for (int rp = 0; rp < RCH; ++rp)
    a += Wrest[co * RCH + rp] * Wmask[rp * RCH + r];
  Wcomb[tid] = a;
}

// ---------------- K1: reduce + phi/theta/g (bf16 outputs) -----------------
// block = 256 thr = 64 pixels x 4 channel-chunks. grid = 1024 blocks.
// phit/tht layout: [b][pixel][r] bf16;  g layout: [b][r][pixel] bf16
__global__ __launch_bounds__(256) void k_reduce(const float* __restrict__ x,
    const float* __restrict__ Wred, const float* __restrict__ Wphi,
    const float* __restrict__ Wth,  const float* __restrict__ Wg,
    const float* __restrict__ posdec,
    ushort* __restrict__ phit, ushort* __restrict__ tht, ushort* __restrict__ g) {
  __shared__ float xr4[4][64][33];   // 33792 B; tiles overlay xr4[1..3]
  ushort* tP = (ushort*)&xr4[1][0][0];
  ushort* tT = tP + 64 * 34;
  ushort* tG = tT + 64 * 34;

  const int t = threadIdx.x;
  const int p = t & 63, q = t >> 6;         // pixel-in-block, channel chunk (=wave)
  const int b = blockIdx.x >> 4;
  const int n0 = (blockIdx.x & 15) << 6;
  const int n = n0 + p;

  // partial 512->32 reduction over this wave's 128 channels
  const float* xb = x + ((size_t)b * CCH) * HW + n;
  float acc[RCH];
#pragma unroll
  for (int r = 0; r < RCH; ++r) acc[r] = 0.f;
  const int c0 = q * 128;
  for (int c = c0; c < c0 + 128; c += 4) {
    float x0 = xb[(size_t)(c + 0) * HW], x1 = xb[(size_t)(c + 1) * HW];
    float x2 = xb[(size_t)(c + 2) * HW], x3 = xb[(size_t)(c + 3) * HW];
#pragma unroll
    for (int r = 0; r < RCH; ++r) {
      const float4 w = *(const float4*)(Wred + r * CCH + c);  // wave-uniform -> s_load
      acc[r] += w.x * x0 + w.y * x1 + w.z * x2 + w.w * x3;
    }
  }
#pragma unroll
  for (int r = 0; r < RCH; ++r) xr4[q][p][r] = acc[r];
  __syncthreads();

  // sum the 4 chunk partials into xr4[0]
  {
    const int rq = t >> 6;
#pragma unroll
    for (int k = 0; k < 8; ++k) {
      int r = rq * 8 + k;
      xr4[0][p][r] = xr4[0][p][r] + xr4[1][p][r] + xr4[2][p][r] + xr4[3][p][r];
    }
  }
  __syncthreads();

  // small gemms: thread owns (pixel p, 8 r rows); weights wave-uniform
  {
    const int rq = t >> 6;
    float xv[RCH];
#pragma unroll
    for (int rr = 0; rr < RCH; ++rr) xv[rr] = xr4[0][p][rr];
    for (int k = 0; k < 8; ++k) {
      int r = rq * 8 + k;
      float dp = 0.f, dt = 0.f, dg = 0.f;
#pragma unroll
      for (int rr = 0; rr < RCH; ++rr) {
        dp += Wphi[r * RCH + rr] * xv[rr];
        dt += Wth[r * RCH + rr] * xv[rr];
        dg += Wg[r * RCH + rr] * xv[rr];
      }
      tP[p * 34 + r] = f2b(dp);
      tT[p * 34 + r] = f2b(dt);
      tG[p * 34 + r] = f2b(dg + posdec[(size_t)r * HW + n]);
    }
  }
  __syncthreads();

  // coalesced stores
  {
    int r = t & 31, pg = t >> 5;
#pragma unroll
    for (int k = 0; k < 8; ++k) {
      int p2 = k * 8 + pg;
      size_t o = ((size_t)b * HW + n0 + p2) * RCH + r;
      phit[o] = tP[p2 * 34 + r];
      tht[o]  = tT[p2 * 34 + r];
    }
  }
  {
    int p2 = t & 63, rq2 = t >> 6;
#pragma unroll
    for (int k = 0; k < 8; ++k) {
      int r = k * 4 + rq2;
      g[((size_t)b * RCH + r) * HW + n0 + p2] = tG[p2 * 34 + r];
    }
  }
}

// ---------------- K2: MFMA attention --------------------------------------
// block: 512 thr (8 waves), QBLK=16 query rows, wave w owns m in [w*128,+128)
__global__ __launch_bounds__(512) void k_attn(const ushort* __restrict__ phit,
    const ushort* __restrict__ tht, const ushort* __restrict__ g,
    const float* __restrict__ pos, float* __restrict__ y2) {
  __shared__ ushort P[QBLK][PSTR];            // 33024 B
  __shared__ float wmax[8][QBLK];             // 512 B
  __shared__ float wsum[8][QBLK];             // 512 B
  __shared__ float ypart[8][RCH][QBLK + 1];   // 17408 B

  const int t = threadIdx.x;
  const int wv = t >> 6, lane = t & 63;
  const int hl = lane >> 4, ll = lane & 15;
  const int b = blockIdx.y;
  const int n0 = blockIdx.x * QBLK;
  const int m0 = wv << 7;
  const f32x4 fzero = {0.f, 0.f, 0.f, 0.f};

  const ushort* phib = phit + (size_t)b * (HW * RCH);
  const ushort* thb  = tht  + (size_t)b * (HW * RCH);
  const ushort* gb   = g    + (size_t)b * (RCH * HW);

  // ---- QK^T via MFMA: A=theta rows (n), B=phi cols (m), K=32 channels ----
  short8 afrag = *(const short8*)&thb[(n0 + ll) * RCH + hl * 8];
  f32x4 acc[8];
#pragma unroll
  for (int fb = 0; fb < 8; ++fb) {
    short8 bfrag = *(const short8*)&phib[(m0 + fb * 16 + ll) * RCH + hl * 8];
    acc[fb] = __builtin_amdgcn_mfma_f32_16x16x32_bf16(afrag, bfrag, fzero, 0, 0, 0);
  }

  // ---- add pos embedding (fp32) ----
  const float* posn = pos + (size_t)n0 * HW + m0 + ll;
#pragma unroll
  for (int fb = 0; fb < 8; ++fb)
#pragma unroll
    for (int i = 0; i < 4; ++i)
      acc[fb][i] += posn[(size_t)(hl * 4 + i) * HW + fb * 16];

  // ---- row max (per-wave then cross-wave) ----
  float mx[4];
#pragma unroll
  for (int i = 0; i < 4; ++i) {
    float m_ = fmaxf(fmaxf(fmaxf(acc[0][i], acc[1][i]), fmaxf(acc[2][i], acc[3][i])),
                     fmaxf(fmaxf(acc[4][i], acc[5][i]), fmaxf(acc[6][i], acc[7][i])));
#pragma unroll
    for (int off = 1; off < 16; off <<= 1) m_ = fmaxf(m_, __shfl_xor(m_, off, 64));
    mx[i] = m_;
  }
  if (ll == 0) {
#pragma unroll
    for (int i = 0; i < 4; ++i) wmax[wv][hl * 4 + i] = mx[i];
  }
  __syncthreads();
#pragma unroll
  for (int i = 0; i < 4; ++i) {
    float m_ = wmax[0][hl * 4 + i];
#pragma unroll
    for (int w = 1; w < 8; ++w) m_ = fmaxf(m_, wmax[w][hl * 4 + i]);
    mx[i] = m_;
  }

  // ---- exp, partial sums, P -> LDS (bf16) ----
  float sm[4] = {0.f, 0.f, 0.f, 0.f};
#pragma unroll
  for (int fb = 0; fb < 8; ++fb)
#pragma unroll
    for (int i = 0; i < 4; ++i) {
      float pval = __expf(acc[fb][i] - mx[i]);
      sm[i] += pval;
      P[hl * 4 + i][m0 + fb * 16 + ll] = f2b(pval);
    }
#pragma unroll
  for (int i = 0; i < 4; ++i) {
#pragma unroll
    for (int off = 1; off < 16; off <<= 1) sm[i] += __shfl_xor(sm[i], off, 64);
  }
  if (ll == 0) {
#pragma unroll
    for (int i = 0; i < 4; ++i) wsum[wv][hl * 4 + i] = sm[i];
  }
  __syncthreads();   // P + wsum complete

  // ---- PV via MFMA: y^T[r][n] += g[r][m] * P[n][m] over wave's m-slice ----
  f32x4 acc2[2] = {fzero, fzero};
#pragma unroll
  for (int ks = 0; ks < 4; ++ks) {
    short8 bfr = *(const short8*)&P[ll][m0 + ks * 32 + hl * 8];
#pragma unroll
    for (int fr = 0; fr < 2; ++fr) {
      short8 ag = *(const short8*)&gb[(size_t)(fr * 16 + ll) * HW + m0 + ks * 32 + hl * 8];
      acc2[fr] = __builtin_amdgcn_mfma_f32_16x16x32_bf16(ag, bfr, acc2[fr], 0, 0, 0);
    }
  }
#pragma unroll
  for (int fr = 0; fr < 2; ++fr)
#pragma unroll
    for (int i = 0; i < 4; ++i)
      ypart[wv][fr * 16 + hl * 4 + i][ll] = acc2[fr][i];
  __syncthreads();

  // ---- cross-wave reduce, normalize, store ----
  {
    const int r = t >> 4, n = t & 15;
    float s = 0.f;
#pragma unroll
    for (int w = 0; w < 8; ++w) s += ypart[w][r][n];
    float ssum = 0.f;
#pragma unroll
    for (int w = 0; w < 8; ++w) ssum += wsum[w][n];
    y2[((size_t)b * RCH + r) * HW + n0 + n] = s / ssum;
  }
}

// ---------------- K3: out = x + Wcomb @ y2 (co split over grid.y) ---------
__global__ __launch_bounds__(256) void k_restore(const float* __restrict__ x,
    const float* __restrict__ Wcomb, const float* __restrict__ y2,
    float* __restrict__ out) {
  const int t = threadIdx.x;
  const int gp = blockIdx.x * 256 + t;
  const int b = gp >> 10, n = gp & 1023;
  const int co0 = blockIdx.y * 64;

  float yv[RCH];
  const float* y2b = y2 + ((size_t)b * RCH) * HW + n;
#pragma unroll
  for (int r = 0; r < RCH; ++r) yv[r] = y2b[(size_t)r * HW];

  const float* xb = x + ((size_t)b * CCH) * HW + n;
  float* ob = out + ((size_t)b * CCH) * HW + n;
  for (int co = co0; co < co0 + 64; ++co) {
    float a = xb[(size_t)co * HW];
#pragma unroll
    for (int qq = 0; qq < RCH; qq += 4) {
      const float4 w = *(const float4*)(Wcomb + co * RCH + qq);  // uniform -> s_load
      a += w.x * yv[qq] + w.y * yv[qq + 1] + w.z * yv[qq + 2] + w.w * yv[qq + 3];
    }
    ob[(size_t)co * HW] = a;
  }
}

extern "C" void kernel_launch(void* const* d_in, const int* in_sizes, int n_in,
                              void* d_out, int out_size, void* d_ws, size_t ws_size,
                              hipStream_t stream) {
  const float* x      = (const float*)d_in[0];
  const float* Wred   = (const float*)d_in[1];
  const float* Wrest  = (const float*)d_in[2];
  const float* Wphi   = (const float*)d_in[3];
  const float* Wth    = (const float*)d_in[4];
  const float* Wg     = (const float*)d_in[5];
  const float* Wmask  = (const float*)d_in[6];
  const float* pos    = (const float*)d_in[7];
  const float* posdec = (const float*)d_in[8];
  float* out = (float*)d_out;

  const size_t NE = (size_t)BATCH * RCH * HW;       // 2M elements
  ushort* phit = (ushort*)d_ws;
  ushort* tht  = phit + NE;
  ushort* gbuf = tht + NE;
  float*  y2   = (float*)(gbuf + NE);               // 12 MB offset, aligned
  float*  Wcomb = y2 + NE;                          // +8 MB

  k_wcomb  <<<dim3(64),       dim3(256), 0, stream>>>(Wrest, Wmask, Wcomb);
  k_reduce <<<dim3(1024),     dim3(256), 0, stream>>>(x, Wred, Wphi, Wth, Wg, posdec,
                                                      phit, tht, gbuf);
  k_attn   <<<dim3(64, 64),   dim3(512), 0, stream>>>(phit, tht, gbuf, pos, y2);
  k_restore<<<dim3(256, 8),   dim3(256), 0, stream>>>(x, Wcomb, y2, out);
}

// Round 3
// 221.141 us; speedup vs baseline: 3.1703x; 1.2705x over previous
//
#include <hip/hip_runtime.h>
#include <cstddef>

#define BATCH 64
#define CCH   512
#define RCH   32
#define HW    1024
#define QBLK  16
#define PSTR  1032   // P_lds row stride in bf16 elems

typedef __attribute__((ext_vector_type(8))) short short8;
typedef __attribute__((ext_vector_type(4))) float f32x4;

__device__ inline ushort f2b(float f) {   // f32 -> bf16 bits, RNE
  union { float f; uint u; } x{f};
  uint r = x.u + 0x7FFFu + ((x.u >> 16) & 1u);
  return (ushort)(r >> 16);
}
__device__ inline uint  fbits(float f) { union { float f; uint u; } x{f}; return x.u; }
__device__ inline float bitsf(uint u)  { union { uint u; float f; } x{u}; return x.f; }

// ---------------- K0: weight prep --------------------------------------------
// job0: Wcomb = W_restore @ W_mask (fp32 512x32)
// job1..3: Wc[mix] = Wmix @ W_reduce (32x512), split to bf16 hi/lo planes
__global__ __launch_bounds__(256) void k_prep(const float* __restrict__ Wred,
    const float* __restrict__ Wrest, const float* __restrict__ Wphi,
    const float* __restrict__ Wth,   const float* __restrict__ Wg,
    const float* __restrict__ Wmask,
    float* __restrict__ Wcomb, ushort* __restrict__ Wh, ushort* __restrict__ Wl) {
  int tid = blockIdx.x * 256 + threadIdx.x;
  int job = tid >> 14, idx = tid & 16383;
  if (job == 0) {
    int co = idx >> 5, r = idx & 31;
    float a = 0.f;
#pragma unroll
    for (int rp = 0; rp < RCH; ++rp)
      a += Wrest[co * RCH + rp] * Wmask[rp * RCH + r];
    Wcomb[idx] = a;
  } else {
    const float* Wm = (job == 1) ? Wphi : (job == 2) ? Wth : Wg;
    int rp = idx >> 9;            // out channel 0..31
    float a = 0.f;
#pragma unroll
    for (int r = 0; r < RCH; ++r)
      a += Wm[rp * RCH + r] * Wred[r * CCH + (idx & 511)];
    uint h = fbits(a) & 0xffff0000u;
    int o = (job - 1) * RCH * CCH + idx;
    Wh[o] = (ushort)(h >> 16);
    Wl[o] = f2b(a - bitsf(h));
  }
}

// ---------------- K1: phi/theta/g = Wc @ x via split-bf16 MFMA ---------------
// grid (8 px-chunks, 64 b), block 256 thr = 4 waves, wave = 32 px (2 B-frags)
// phiT/thT: [b][px][64] bf16 (hi 0..31, lo 32..63);  g: [b][r][px] bf16
__global__ __launch_bounds__(256) void k_qkg(const float* __restrict__ x,
    const ushort* __restrict__ Wh, const ushort* __restrict__ Wl,
    const float* __restrict__ posdec,
    ushort* __restrict__ phiT, ushort* __restrict__ thT, ushort* __restrict__ g) {
  __shared__ float gt[4][RCH][33];

  const int t = threadIdx.x;
  const int wv = t >> 6, lane = t & 63;
  const int ll = lane & 15, hl = lane >> 4;
  const int b = blockIdx.y;
  const int px0 = blockIdx.x * 128 + wv * 32;
  const f32x4 fz = {0.f, 0.f, 0.f, 0.f};

  f32x4 acc[3][2][2];
#pragma unroll
  for (int m1 = 0; m1 < 3; ++m1)
#pragma unroll
    for (int m2 = 0; m2 < 2; ++m2)
#pragma unroll
      for (int m3 = 0; m3 < 2; ++m3) acc[m1][m2][m3] = fz;

  for (int kk = 0; kk < 16; ++kk) {
    // X frags: load 8 fp32 (stride HW), split hi/lo
    short8 xh[2], xl[2];
#pragma unroll
    for (int pf = 0; pf < 2; ++pf) {
      const float* xp = x + ((size_t)b * CCH + kk * 32 + hl * 8) * HW + px0 + pf * 16 + ll;
      float xv[8];
#pragma unroll
      for (int j = 0; j < 8; ++j) xv[j] = xp[(size_t)j * HW];
#pragma unroll
      for (int j = 0; j < 8; ++j) {
        uint h = fbits(xv[j]) & 0xffff0000u;
        xh[pf][j] = (short)(h >> 16);
        xl[pf][j] = (short)f2b(xv[j] - bitsf(h));
      }
    }
    // W frags + MFMA (3-term split)
#pragma unroll
    for (int mix = 0; mix < 3; ++mix)
#pragma unroll
      for (int m = 0; m < 2; ++m) {
        const ushort* wb = Wh + (size_t)(mix * RCH + m * 16 + ll) * CCH + kk * 32 + hl * 8;
        short8 wh = *(const short8*)wb;
        short8 wl = *(const short8*)(wb + 3 * RCH * CCH);
#pragma unroll
        for (int pf = 0; pf < 2; ++pf) {
          f32x4 a = acc[mix][m][pf];
          a = __builtin_amdgcn_mfma_f32_16x16x32_bf16(wl, xh[pf], a, 0, 0, 0);
          a = __builtin_amdgcn_mfma_f32_16x16x32_bf16(wh, xl[pf], a, 0, 0, 0);
          a = __builtin_amdgcn_mfma_f32_16x16x32_bf16(wh, xh[pf], a, 0, 0, 0);
          acc[mix][m][pf] = a;
        }
      }
  }

  // ---- epilogue: phi/theta -> [px][64] hi/lo ----
#pragma unroll
  for (int mix = 0; mix < 2; ++mix) {
    ushort* outb = (mix ? thT : phiT) + ((size_t)b * HW + px0) * 64;
#pragma unroll
    for (int m = 0; m < 2; ++m)
#pragma unroll
      for (int pf = 0; pf < 2; ++pf) {
        f32x4 v = acc[mix][m][pf];
        uint h0 = fbits(v[0]) & 0xffff0000u, h1 = fbits(v[1]) & 0xffff0000u;
        uint h2 = fbits(v[2]) & 0xffff0000u, h3 = fbits(v[3]) & 0xffff0000u;
        uint2 hp, lp;
        hp.x = (h0 >> 16) | h1;
        hp.y = (h2 >> 16) | h3;
        lp.x = (uint)f2b(v[0] - bitsf(h0)) | ((uint)f2b(v[1] - bitsf(h1)) << 16);
        lp.y = (uint)f2b(v[2] - bitsf(h2)) | ((uint)f2b(v[3] - bitsf(h3)) << 16);
        ushort* o = outb + (size_t)(pf * 16 + ll) * 64 + m * 16 + hl * 4;
        *(uint2*)o = hp;
        *(uint2*)(o + 32) = lp;
      }
  }

  // ---- epilogue: g -> LDS transpose, +posdec, bf16 [r][px] ----
#pragma unroll
  for (int m = 0; m < 2; ++m)
#pragma unroll
    for (int pf = 0; pf < 2; ++pf)
#pragma unroll
      for (int i = 0; i < 4; ++i)
        gt[wv][m * 16 + hl * 4 + i][pf * 16 + ll] = acc[2][m][pf][i];
  __syncthreads();
#pragma unroll
  for (int rr = 0; rr < 8; ++rr) {
    int r = rr * 4 + hl, p2 = ll * 2;
    float a = gt[wv][r][p2], bv = gt[wv][r][p2 + 1];
    const float2 pd = *(const float2*)&posdec[(size_t)r * HW + px0 + p2];
    uint pk = (uint)f2b(a + pd.x) | ((uint)f2b(bv + pd.y) << 16);
    *(uint*)(g + ((size_t)b * RCH + r) * HW + px0 + p2) = pk;
  }
}

// ---------------- K2: MFMA attention (QK^T split 3-term) ---------------------
__global__ __launch_bounds__(512) void k_attn(const ushort* __restrict__ phiT,
    const ushort* __restrict__ thT, const ushort* __restrict__ g,
    const float* __restrict__ pos, float* __restrict__ y2) {
  __shared__ ushort P[QBLK][PSTR];
  __shared__ float wmax[8][QBLK];
  __shared__ float wsum[8][QBLK];
  __shared__ float ypart[8][RCH][QBLK + 1];

  const int t = threadIdx.x;
  const int wv = t >> 6, lane = t & 63;
  const int hl = lane >> 4, ll = lane & 15;
  const int b = blockIdx.y;
  const int n0 = blockIdx.x * QBLK;
  const int m0 = wv << 7;
  const f32x4 fzero = {0.f, 0.f, 0.f, 0.f};

  const ushort* phib = phiT + (size_t)b * (HW * 64);
  const ushort* thb  = thT  + (size_t)b * (HW * 64);
  const ushort* gb   = g    + (size_t)b * (RCH * HW);

  // ---- QK^T: 3-term hi/lo MFMA ----
  const ushort* ap = &thb[(size_t)(n0 + ll) * 64 + hl * 8];
  short8 ah = *(const short8*)ap;
  short8 al = *(const short8*)(ap + 32);
  f32x4 acc[8];
#pragma unroll
  for (int fb = 0; fb < 8; ++fb) {
    const ushort* bp = &phib[(size_t)(m0 + fb * 16 + ll) * 64 + hl * 8];
    short8 bh = *(const short8*)bp;
    short8 bl = *(const short8*)(bp + 32);
    f32x4 a = __builtin_amdgcn_mfma_f32_16x16x32_bf16(al, bh, fzero, 0, 0, 0);
    a = __builtin_amdgcn_mfma_f32_16x16x32_bf16(ah, bl, a, 0, 0, 0);
    a = __builtin_amdgcn_mfma_f32_16x16x32_bf16(ah, bh, a, 0, 0, 0);
    acc[fb] = a;
  }

  // ---- add pos embedding (fp32) ----
  const float* posn = pos + (size_t)n0 * HW + m0 + ll;
#pragma unroll
  for (int fb = 0; fb < 8; ++fb)
#pragma unroll
    for (int i = 0; i < 4; ++i)
      acc[fb][i] += posn[(size_t)(hl * 4 + i) * HW + fb * 16];

  // ---- row max ----
  float mx[4];
#pragma unroll
  for (int i = 0; i < 4; ++i) {
    float m_ = fmaxf(fmaxf(fmaxf(acc[0][i], acc[1][i]), fmaxf(acc[2][i], acc[3][i])),
                     fmaxf(fmaxf(acc[4][i], acc[5][i]), fmaxf(acc[6][i], acc[7][i])));
#pragma unroll
    for (int off = 1; off < 16; off <<= 1) m_ = fmaxf(m_, __shfl_xor(m_, off, 64));
    mx[i] = m_;
  }
  if (ll == 0) {
#pragma unroll
    for (int i = 0; i < 4; ++i) wmax[wv][hl * 4 + i] = mx[i];
  }
  __syncthreads();
#pragma unroll
  for (int i = 0; i < 4; ++i) {
    float m_ = wmax[0][hl * 4 + i];
#pragma unroll
    for (int w = 1; w < 8; ++w) m_ = fmaxf(m_, wmax[w][hl * 4 + i]);
    mx[i] = m_;
  }

  // ---- exp, partial sums, P -> LDS (bf16) ----
  float sm[4] = {0.f, 0.f, 0.f, 0.f};
#pragma unroll
  for (int fb = 0; fb < 8; ++fb)
#pragma unroll
    for (int i = 0; i < 4; ++i) {
      float pval = __expf(acc[fb][i] - mx[i]);
      sm[i] += pval;
      P[hl * 4 + i][m0 + fb * 16 + ll] = f2b(pval);
    }
#pragma unroll
  for (int i = 0; i < 4; ++i) {
#pragma unroll
    for (int off = 1; off < 16; off <<= 1) sm[i] += __shfl_xor(sm[i], off, 64);
  }
  if (ll == 0) {
#pragma unroll
    for (int i = 0; i < 4; ++i) wsum[wv][hl * 4 + i] = sm[i];
  }
  __syncthreads();

  // ---- PV via MFMA over wave's m-slice ----
  f32x4 acc2[2] = {fzero, fzero};
#pragma unroll
  for (int ks = 0; ks < 4; ++ks) {
    short8 bfr = *(const short8*)&P[ll][m0 + ks * 32 + hl * 8];
#pragma unroll
    for (int fr = 0; fr < 2; ++fr) {
      short8 ag = *(const short8*)&gb[(size_t)(fr * 16 + ll) * HW + m0 + ks * 32 + hl * 8];
      acc2[fr] = __builtin_amdgcn_mfma_f32_16x16x32_bf16(ag, bfr, acc2[fr], 0, 0, 0);
    }
  }
#pragma unroll
  for (int fr = 0; fr < 2; ++fr)
#pragma unroll
    for (int i = 0; i < 4; ++i)
      ypart[wv][fr * 16 + hl * 4 + i][ll] = acc2[fr][i];
  __syncthreads();

  // ---- cross-wave reduce, normalize, store ----
  {
    const int r = t >> 4, n = t & 15;
    float s = 0.f;
#pragma unroll
    for (int w = 0; w < 8; ++w) s += ypart[w][r][n];
    float ssum = 0.f;
#pragma unroll
    for (int w = 0; w < 8; ++w) ssum += wsum[w][n];
    y2[((size_t)b * RCH + r) * HW + n0 + n] = s / ssum;
  }
}

// ---------------- K3: out = x + Wcomb @ y2 (co split over grid.y) ------------
__global__ __launch_bounds__(256) void k_restore(const float* __restrict__ x,
    const float* __restrict__ Wcomb, const float* __restrict__ y2,
    float* __restrict__ out) {
  const int t = threadIdx.x;
  const int gp = blockIdx.x * 256 + t;
  const int b = gp >> 10, n = gp & 1023;
  const int co0 = blockIdx.y * 64;

  float yv[RCH];
  const float* y2b = y2 + ((size_t)b * RCH) * HW + n;
#pragma unroll
  for (int r = 0; r < RCH; ++r) yv[r] = y2b[(size_t)r * HW];

  const float* xb = x + ((size_t)b * CCH) * HW + n;
  float* ob = out + ((size_t)b * CCH) * HW + n;
  for (int co = co0; co < co0 + 64; ++co) {
    float a = xb[(size_t)co * HW];
#pragma unroll
    for (int qq = 0; qq < RCH; qq += 4) {
      const float4 w = *(const float4*)(Wcomb + co * RCH + qq);
      a += w.x * yv[qq] + w.y * yv[qq + 1] + w.z * yv[qq + 2] + w.w * yv[qq + 3];
    }
    ob[(size_t)co * HW] = a;
  }
}

extern "C" void kernel_launch(void* const* d_in, const int* in_sizes, int n_in,
                              void* d_out, int out_size, void* d_ws, size_t ws_size,
                              hipStream_t stream) {
  const float* x      = (const float*)d_in[0];
  const float* Wred   = (const float*)d_in[1];
  const float* Wrest  = (const float*)d_in[2];
  const float* Wphi   = (const float*)d_in[3];
  const float* Wth    = (const float*)d_in[4];
  const float* Wg     = (const float*)d_in[5];
  const float* Wmask  = (const float*)d_in[6];
  const float* pos    = (const float*)d_in[7];
  const float* posdec = (const float*)d_in[8];
  float* out = (float*)d_out;

  const size_t PT = (size_t)BATCH * HW * 64;     // phiT/thT shorts (hi+lo)
  const size_t NE = (size_t)BATCH * RCH * HW;    // 2M
  ushort* phiT = (ushort*)d_ws;
  ushort* thT  = phiT + PT;
  ushort* gbuf = thT + PT;
  float*  y2   = (float*)(gbuf + NE);
  float*  Wcomb = y2 + NE;
  ushort* Wh   = (ushort*)(Wcomb + CCH * RCH);
  ushort* Wl   = Wh + 3 * RCH * CCH;

  k_prep   <<<dim3(256),     dim3(256), 0, stream>>>(Wred, Wrest, Wphi, Wth, Wg, Wmask,
                                                     Wcomb, Wh, Wl);
  k_qkg    <<<dim3(8, 64),   dim3(256), 0, stream>>>(x, Wh, Wl, posdec, phiT, thT, gbuf);
  k_attn   <<<dim3(64, 64),  dim3(512), 0, stream>>>(phiT, thT, gbuf, pos, y2);
  k_restore<<<dim3(256, 8),  dim3(256), 0, stream>>>(x, Wcomb, y2, out);
}

// Round 4
// 186.489 us; speedup vs baseline: 3.7594x; 1.1858x over previous
//
#include <hip/hip_runtime.h>
#include <cstddef>

#define BATCH 64
#define CCH   512
#define RCH   32
#define HW    1024

typedef __attribute__((ext_vector_type(8))) short short8;
typedef __attribute__((ext_vector_type(4))) float f32x4;

__device__ inline ushort f2b(float f) {   // f32 -> bf16 bits, RNE
  union { float f; uint u; } x{f};
  uint r = x.u + 0x7FFFu + ((x.u >> 16) & 1u);
  return (ushort)(r >> 16);
}
__device__ inline uint  fbits(float f) { union { float f; uint u; } x{f}; return x.u; }
__device__ inline float bitsf(uint u)  { union { uint u; float f; } x{u}; return x.f; }

// ---------------- K0: weight prep + pos repack -------------------------------
// blk<256: job0 Wcomb = Wrest@Wmask; job1..3 Wc[mix]=Wmix@Wred -> bf16 hi/lo
// blk>=256: pos fp32 [n][m] -> posr bf16 frag layout [n>>2][m][n&3]
__global__ __launch_bounds__(256) void k_prep(const float* __restrict__ Wred,
    const float* __restrict__ Wrest, const float* __restrict__ Wphi,
    const float* __restrict__ Wth,   const float* __restrict__ Wg,
    const float* __restrict__ Wmask, const float* __restrict__ pos,
    float* __restrict__ Wcomb, ushort* __restrict__ Wh, ushort* __restrict__ Wl,
    ushort* __restrict__ posr) {
  const int blk = blockIdx.x;
  if (blk >= 256) {
    int pb = blk - 256;
    int g4 = pb >> 2;
    int m = ((pb & 3) << 8) + threadIdx.x;
    uint a0 = f2b(pos[(size_t)(g4 * 4 + 0) * HW + m]);
    uint a1 = f2b(pos[(size_t)(g4 * 4 + 1) * HW + m]);
    uint a2 = f2b(pos[(size_t)(g4 * 4 + 2) * HW + m]);
    uint a3 = f2b(pos[(size_t)(g4 * 4 + 3) * HW + m]);
    uint2 o;
    o.x = a0 | (a1 << 16);
    o.y = a2 | (a3 << 16);
    *(uint2*)&posr[((size_t)g4 * HW + m) * 4] = o;
    return;
  }
  int tid = blk * 256 + threadIdx.x;
  int job = tid >> 14, idx = tid & 16383;
  if (job == 0) {
    int co = idx >> 5, r = idx & 31;
    float a = 0.f;
#pragma unroll
    for (int rp = 0; rp < RCH; ++rp)
      a += Wrest[co * RCH + rp] * Wmask[rp * RCH + r];
    Wcomb[idx] = a;
  } else {
    const float* Wm = (job == 1) ? Wphi : (job == 2) ? Wth : Wg;
    int rp = idx >> 9;
    float a = 0.f;
#pragma unroll
    for (int r = 0; r < RCH; ++r)
      a += Wm[rp * RCH + r] * Wred[r * CCH + (idx & 511)];
    uint h = fbits(a) & 0xffff0000u;
    int o = (job - 1) * RCH * CCH + idx;
    Wh[o] = (ushort)(h >> 16);
    Wl[o] = f2b(a - bitsf(h));
  }
}

// ---------------- K1: phi/theta/g = Wc @ x via split-bf16 MFMA ---------------
__global__ __launch_bounds__(256) void k_qkg(const float* __restrict__ x,
    const ushort* __restrict__ Wh, const ushort* __restrict__ Wl,
    const float* __restrict__ posdec,
    ushort* __restrict__ phiT, ushort* __restrict__ thT, ushort* __restrict__ g) {
  __shared__ float gt[4][RCH][33];

  const int t = threadIdx.x;
  const int wv = t >> 6, lane = t & 63;
  const int ll = lane & 15, hl = lane >> 4;
  const int b = blockIdx.y;
  const int px0 = blockIdx.x * 128 + wv * 32;
  const f32x4 fz = {0.f, 0.f, 0.f, 0.f};

  f32x4 acc[3][2][2];
#pragma unroll
  for (int m1 = 0; m1 < 3; ++m1)
#pragma unroll
    for (int m2 = 0; m2 < 2; ++m2)
#pragma unroll
      for (int m3 = 0; m3 < 2; ++m3) acc[m1][m2][m3] = fz;

  for (int kk = 0; kk < 16; ++kk) {
    short8 xh[2], xl[2];
#pragma unroll
    for (int pf = 0; pf < 2; ++pf) {
      const float* xp = x + ((size_t)b * CCH + kk * 32 + hl * 8) * HW + px0 + pf * 16 + ll;
      float xv[8];
#pragma unroll
      for (int j = 0; j < 8; ++j) xv[j] = xp[(size_t)j * HW];
#pragma unroll
      for (int j = 0; j < 8; ++j) {
        uint h = fbits(xv[j]) & 0xffff0000u;
        xh[pf][j] = (short)(h >> 16);
        xl[pf][j] = (short)f2b(xv[j] - bitsf(h));
      }
    }
#pragma unroll
    for (int mix = 0; mix < 3; ++mix)
#pragma unroll
      for (int m = 0; m < 2; ++m) {
        const ushort* wb = Wh + (size_t)(mix * RCH + m * 16 + ll) * CCH + kk * 32 + hl * 8;
        short8 wh = *(const short8*)wb;
        short8 wl = *(const short8*)(wb + 3 * RCH * CCH);
#pragma unroll
        for (int pf = 0; pf < 2; ++pf) {
          f32x4 a = acc[mix][m][pf];
          a = __builtin_amdgcn_mfma_f32_16x16x32_bf16(wl, xh[pf], a, 0, 0, 0);
          a = __builtin_amdgcn_mfma_f32_16x16x32_bf16(wh, xl[pf], a, 0, 0, 0);
          a = __builtin_amdgcn_mfma_f32_16x16x32_bf16(wh, xh[pf], a, 0, 0, 0);
          acc[mix][m][pf] = a;
        }
      }
  }

#pragma unroll
  for (int mix = 0; mix < 2; ++mix) {
    ushort* outb = (mix ? thT : phiT) + ((size_t)b * HW + px0) * 64;
#pragma unroll
    for (int m = 0; m < 2; ++m)
#pragma unroll
      for (int pf = 0; pf < 2; ++pf) {
        f32x4 v = acc[mix][m][pf];
        uint h0 = fbits(v[0]) & 0xffff0000u, h1 = fbits(v[1]) & 0xffff0000u;
        uint h2 = fbits(v[2]) & 0xffff0000u, h3 = fbits(v[3]) & 0xffff0000u;
        uint2 hp, lp;
        hp.x = (h0 >> 16) | h1;
        hp.y = (h2 >> 16) | h3;
        lp.x = (uint)f2b(v[0] - bitsf(h0)) | ((uint)f2b(v[1] - bitsf(h1)) << 16);
        lp.y = (uint)f2b(v[2] - bitsf(h2)) | ((uint)f2b(v[3] - bitsf(h3)) << 16);
        ushort* o = outb + (size_t)(pf * 16 + ll) * 64 + m * 16 + hl * 4;
        *(uint2*)o = hp;
        *(uint2*)(o + 32) = lp;
      }
  }

#pragma unroll
  for (int m = 0; m < 2; ++m)
#pragma unroll
    for (int pf = 0; pf < 2; ++pf)
#pragma unroll
      for (int i = 0; i < 4; ++i)
        gt[wv][m * 16 + hl * 4 + i][pf * 16 + ll] = acc[2][m][pf][i];
  __syncthreads();
#pragma unroll
  for (int rr = 0; rr < 8; ++rr) {
    int r = rr * 4 + hl, p2 = ll * 2;
    float a = gt[wv][r][p2], bv = gt[wv][r][p2 + 1];
    const float2 pd = *(const float2*)&posdec[(size_t)r * HW + px0 + p2];
    uint pk = (uint)f2b(a + pd.x) | ((uint)f2b(bv + pd.y) << 16);
    *(uint*)(g + ((size_t)b * RCH + r) * HW + px0 + p2) = pk;
  }
}

// ---------------- K2: flash attention, QBLK=32, 4 waves, 8 partials ----------
__global__ __launch_bounds__(256, 3) void k_attn(const ushort* __restrict__ phiT,
    const ushort* __restrict__ thT, const ushort* __restrict__ g,
    const ushort* __restrict__ posr, float* __restrict__ y2) {
  __shared__ ushort slab[4][32][64];     // 16 KB: per-wave P transpose slab
  __shared__ float ypw[8][32][33];       // 33.8 KB: per-(wave,chunk) y partials
  __shared__ float mw[8][32];            // chunk-local row max
  __shared__ float sw[8][32];            // chunk-local row sum

  const int t = threadIdx.x;
  const int wv = t >> 6, lane = t & 63;
  const int ll = lane & 15, hl = lane >> 4;
  const int b = blockIdx.y;
  const int n0 = blockIdx.x * 32;
  const f32x4 fz = {0.f, 0.f, 0.f, 0.f};

  const ushort* phib = phiT + (size_t)b * (HW * 64);
  const ushort* thb  = thT  + (size_t)b * (HW * 64);
  const ushort* gb   = g    + (size_t)b * (RCH * HW);

  // theta A-frags (hi/lo), rows n0..n0+31
  short8 ah[2], al[2];
#pragma unroll
  for (int nf = 0; nf < 2; ++nf) {
    const ushort* ap = &thb[(size_t)(n0 + nf * 16 + ll) * 64 + hl * 8];
    ah[nf] = *(const short8*)ap;
    al[nf] = *(const short8*)(ap + 32);
  }

  for (int ck = 0; ck < 2; ++ck) {
    const int mch = wv * 256 + ck * 128;
    const int pidx = wv * 2 + ck;

    // ---- QK^T (3-term hi/lo) ----
    f32x4 acc[2][8];
#pragma unroll
    for (int mf = 0; mf < 8; ++mf) {
      const ushort* bp = &phib[(size_t)(mch + mf * 16 + ll) * 64 + hl * 8];
      short8 bh = *(const short8*)bp;
      short8 bl = *(const short8*)(bp + 32);
#pragma unroll
      for (int nf = 0; nf < 2; ++nf) {
        f32x4 a = __builtin_amdgcn_mfma_f32_16x16x32_bf16(al[nf], bh, fz, 0, 0, 0);
        a = __builtin_amdgcn_mfma_f32_16x16x32_bf16(ah[nf], bl, a, 0, 0, 0);
        a = __builtin_amdgcn_mfma_f32_16x16x32_bf16(ah[nf], bh, a, 0, 0, 0);
        acc[nf][mf] = a;
      }
    }

    // ---- + pos (bf16 frag layout) ----
#pragma unroll
    for (int nf = 0; nf < 2; ++nf) {
      const size_t prow = (size_t)(n0 / 4 + nf * 4 + hl) * HW;
#pragma unroll
      for (int mf = 0; mf < 8; ++mf) {
        uint2 pp = *(const uint2*)&posr[(prow + mch + mf * 16 + ll) * 4];
        acc[nf][mf][0] += bitsf(pp.x << 16);
        acc[nf][mf][1] += bitsf(pp.x & 0xffff0000u);
        acc[nf][mf][2] += bitsf(pp.y << 16);
        acc[nf][mf][3] += bitsf(pp.y & 0xffff0000u);
      }
    }

    // ---- chunk-local softmax partials (rows owned by (hl,i)) ----
#pragma unroll
    for (int nf = 0; nf < 2; ++nf)
#pragma unroll
      for (int i = 0; i < 4; ++i) {
        float m_ = acc[nf][0][i];
#pragma unroll
        for (int mf = 1; mf < 8; ++mf) m_ = fmaxf(m_, acc[nf][mf][i]);
        m_ = fmaxf(m_, __shfl_xor(m_, 1));
        m_ = fmaxf(m_, __shfl_xor(m_, 2));
        m_ = fmaxf(m_, __shfl_xor(m_, 4));
        m_ = fmaxf(m_, __shfl_xor(m_, 8));
        float s_ = 0.f;
#pragma unroll
        for (int mf = 0; mf < 8; ++mf) {
          float p = __expf(acc[nf][mf][i] - m_);
          acc[nf][mf][i] = p;
          s_ += p;
        }
        s_ += __shfl_xor(s_, 1);
        s_ += __shfl_xor(s_, 2);
        s_ += __shfl_xor(s_, 4);
        s_ += __shfl_xor(s_, 8);
        if (ll == 0) {
          mw[pidx][nf * 16 + hl * 4 + i] = m_;
          sw[pidx][nf * 16 + hl * 4 + i] = s_;
        }
      }

    // ---- PV in two 64-m halves through swizzled per-wave slab ----
    f32x4 y[2][2] = {{fz, fz}, {fz, fz}};
#pragma unroll
    for (int h = 0; h < 2; ++h) {
#pragma unroll
      for (int nf = 0; nf < 2; ++nf)
#pragma unroll
        for (int mf = 0; mf < 4; ++mf)
#pragma unroll
          for (int i = 0; i < 4; ++i) {
            int n = nf * 16 + hl * 4 + i;
            int m = mf * 16 + ll;
            slab[wv][n][m ^ ((n & 7) << 3)] = f2b(acc[nf][h * 4 + mf][i]);
          }
      asm volatile("s_waitcnt lgkmcnt(0)" ::: "memory");
#pragma unroll
      for (int ks = 0; ks < 2; ++ks) {
        short8 bfr[2];
#pragma unroll
        for (int nblk = 0; nblk < 2; ++nblk) {
          int n = nblk * 16 + ll;
          bfr[nblk] = *(const short8*)&slab[wv][n][(ks * 32 + hl * 8) ^ ((n & 7) << 3)];
        }
#pragma unroll
        for (int rf = 0; rf < 2; ++rf) {
          short8 ag = *(const short8*)&gb[(size_t)(rf * 16 + ll) * HW + mch + h * 64 + ks * 32 + hl * 8];
#pragma unroll
          for (int nblk = 0; nblk < 2; ++nblk)
            y[rf][nblk] = __builtin_amdgcn_mfma_f32_16x16x32_bf16(ag, bfr[nblk], y[rf][nblk], 0, 0, 0);
        }
      }
      asm volatile("s_waitcnt lgkmcnt(0)" ::: "memory");
    }

    // ---- stash chunk partial ----
#pragma unroll
    for (int rf = 0; rf < 2; ++rf)
#pragma unroll
      for (int nblk = 0; nblk < 2; ++nblk)
#pragma unroll
        for (int i = 0; i < 4; ++i)
          ypw[pidx][rf * 16 + hl * 4 + i][nblk * 16 + ll] = y[rf][nblk][i];
  }
  __syncthreads();

  // ---- merge 8 partials, normalize, store ----
  {
    const int n = t & 31, rr = t >> 5;
    float M = mw[0][n];
#pragma unroll
    for (int w = 1; w < 8; ++w) M = fmaxf(M, mw[w][n]);
    float sc[8];
    float s = 0.f;
#pragma unroll
    for (int w = 0; w < 8; ++w) {
      sc[w] = __expf(mw[w][n] - M);
      s += sw[w][n] * sc[w];
    }
    float inv = 1.f / s;
    float* outp = y2 + ((size_t)b * RCH) * HW + n0 + n;
#pragma unroll
    for (int k = 0; k < 4; ++k) {
      int r = rr * 4 + k;
      float a_ = 0.f;
#pragma unroll
      for (int w = 0; w < 8; ++w) a_ += ypw[w][r][n] * sc[w];
      outp[(size_t)r * HW] = a_ * inv;
    }
  }
}

// ---------------- K3: out = x + Wcomb @ y2 (co split over grid.y) ------------
__global__ __launch_bounds__(256) void k_restore(const float* __restrict__ x,
    const float* __restrict__ Wcomb, const float* __restrict__ y2,
    float* __restrict__ out) {
  const int t = threadIdx.x;
  const int gp = blockIdx.x * 256 + t;
  const int b = gp >> 10, n = gp & 1023;
  const int co0 = blockIdx.y * 64;

  float yv[RCH];
  const float* y2b = y2 + ((size_t)b * RCH) * HW + n;
#pragma unroll
  for (int r = 0; r < RCH; ++r) yv[r] = y2b[(size_t)r * HW];

  const float* xb = x + ((size_t)b * CCH) * HW + n;
  float* ob = out + ((size_t)b * CCH) * HW + n;
  for (int co = co0; co < co0 + 64; ++co) {
    float a = xb[(size_t)co * HW];
#pragma unroll
    for (int qq = 0; qq < RCH; qq += 4) {
      const float4 w = *(const float4*)(Wcomb + co * RCH + qq);
      a += w.x * yv[qq] + w.y * yv[qq + 1] + w.z * yv[qq + 2] + w.w * yv[qq + 3];
    }
    ob[(size_t)co * HW] = a;
  }
}

extern "C" void kernel_launch(void* const* d_in, const int* in_sizes, int n_in,
                              void* d_out, int out_size, void* d_ws, size_t ws_size,
                              hipStream_t stream) {
  const float* x      = (const float*)d_in[0];
  const float* Wred   = (const float*)d_in[1];
  const float* Wrest  = (const float*)d_in[2];
  const float* Wphi   = (const float*)d_in[3];
  const float* Wth    = (const float*)d_in[4];
  const float* Wg     = (const float*)d_in[5];
  const float* Wmask  = (const float*)d_in[6];
  const float* pos    = (const float*)d_in[7];
  const float* posdec = (const float*)d_in[8];
  float* out = (float*)d_out;

  const size_t PT = (size_t)BATCH * HW * 64;     // phiT/thT shorts (hi+lo)
  const size_t NE = (size_t)BATCH * RCH * HW;    // 2M
  ushort* phiT = (ushort*)d_ws;
  ushort* thT  = phiT + PT;
  ushort* gbuf = thT + PT;
  float*  y2   = (float*)(gbuf + NE);
  float*  Wcomb = y2 + NE;
  ushort* Wh   = (ushort*)(Wcomb + CCH * RCH);
  ushort* Wl   = Wh + 3 * RCH * CCH;
  ushort* posr = Wl + 3 * RCH * CCH;             // 1M shorts (2 MB)

  k_prep   <<<dim3(1280),    dim3(256), 0, stream>>>(Wred, Wrest, Wphi, Wth, Wg, Wmask,
                                                     pos, Wcomb, Wh, Wl, posr);
  k_qkg    <<<dim3(8, 64),   dim3(256), 0, stream>>>(x, Wh, Wl, posdec, phiT, thT, gbuf);
  k_attn   <<<dim3(32, 64),  dim3(256), 0, stream>>>(phiT, thT, gbuf, posr, y2);
  k_restore<<<dim3(256, 8),  dim3(256), 0, stream>>>(x, Wcomb, y2, out);
}